// Round 17
// baseline (429.413 us; speedup 1.0000x reference)
//
#include <hip/hip_runtime.h>
#include <stdint.h>

typedef __bf16 bf16;
typedef __bf16 bf16x4 __attribute__((ext_vector_type(4)));
typedef __bf16 bf16x8 __attribute__((ext_vector_type(8)));
typedef float  f32x4  __attribute__((ext_vector_type(4)));
typedef float  f32x16 __attribute__((ext_vector_type(16)));

constexpr int BB = 8;
constexpr int NN = 2048;
constexpr int EE = 768;
constexpr int MM = BB * NN;   // 16384

typedef const __attribute__((address_space(1))) void* as1_cvp;
typedef __attribute__((address_space(3))) void* as3_vp;

static __device__ __forceinline__ void gld16(const void* g, void* l) {
  __builtin_amdgcn_global_load_lds((as1_cvp)g, (as3_vp)l, 16, 0, 0);
}

// ---------------- x -> bf16 hi/lo split ----------------
__global__ __launch_bounds__(256) void k_splitx(const float4* __restrict__ x,
                                                bf16x4* __restrict__ hi,
                                                bf16x4* __restrict__ lo, int n4) {
  int i = blockIdx.x * 256 + threadIdx.x;
  int st = gridDim.x * 256;
  for (; i < n4; i += st) {
    float4 v = x[i];
    bf16x4 h, l;
    h[0] = (bf16)v.x; l[0] = (bf16)(v.x - (float)h[0]);
    h[1] = (bf16)v.y; l[1] = (bf16)(v.y - (float)h[1]);
    h[2] = (bf16)v.z; l[2] = (bf16)(v.z - (float)h[2]);
    h[3] = (bf16)v.w; l[3] = (bf16)(v.w - (float)h[3]);
    hi[i] = h; lo[i] = l;
  }
}

// ---------------- merged weight prep ----------------
// z: 0 = Wq^T pair, 1 = Wk^T pair, 2 = Wv^T (hi only), 3 = Wo plain cvt
__global__ __launch_bounds__(256) void k_prep(const float* __restrict__ wq,
                                              const float* __restrict__ wk,
                                              const float* __restrict__ wv,
                                              const float* __restrict__ wo,
                                              bf16* __restrict__ qTh, bf16* __restrict__ qTl,
                                              bf16* __restrict__ kTh, bf16* __restrict__ kTl,
                                              bf16* __restrict__ vT,  bf16* __restrict__ ob) {
  __shared__ float t[64][65];
  int z = blockIdx.z;
  int tid = threadIdx.x;
  if (z == 3) {  // Wo: plain fp32 -> bf16, coalesced
    int blk = blockIdx.y * 12 + blockIdx.x;
    const float4* s4 = (const float4*)wo;
#pragma unroll
    for (int j = 0; j < 4; j++) {
      int i = blk * 1024 + j * 256 + tid;
      float4 v = s4[i];
      bf16x4 h;
      h[0] = (bf16)v.x; h[1] = (bf16)v.y; h[2] = (bf16)v.z; h[3] = (bf16)v.w;
      ((bf16x4*)ob)[i] = h;
    }
    return;
  }
  const float* src = z == 0 ? wq : (z == 1 ? wk : wv);
  bf16* hi = z == 0 ? qTh : (z == 1 ? kTh : vT);
  bf16* lo = z == 0 ? qTl : kTl;  // unused when z==2
  bool pair = z < 2;
  int e0 = blockIdx.x * 64, f0 = blockIdx.y * 64;
#pragma unroll
  for (int h = 0; h < 4; h++) {
    int lin = h * 1024 + tid * 4;
    int r = lin >> 6, c = lin & 63;
    float4 v = *(const float4*)(src + (size_t)(f0 + r) * EE + e0 + c);
    t[r][c] = v.x; t[r][c + 1] = v.y; t[r][c + 2] = v.z; t[r][c + 3] = v.w;
  }
  __syncthreads();
#pragma unroll
  for (int h = 0; h < 4; h++) {
    int lin = h * 1024 + tid * 4;
    int er = lin >> 6, fc = lin & 63;
    bf16x4 oh, ol;
#pragma unroll
    for (int j = 0; j < 4; j++) {
      float v = t[fc + j][er];
      bf16 hh = (bf16)v;
      oh[j] = hh;
      ol[j] = (bf16)(v - (float)hh);
    }
    *(bf16x4*)(hi + (size_t)(e0 + er) * EE + f0 + fc) = oh;
    if (pair) *(bf16x4*)(lo + (size_t)(e0 + er) * EE + f0 + fc) = ol;
  }
}

// ---------------- split GEMM, 32x32x16 MFMA variant ----------------
// C[M,N] = (Ah+Al)[M,K] @ (Bh+Bl)[N,K]^T, 3-product compensation.
// Same staging/swizzle/block structure as the proven 128^2 kernel; inner loop
// uses v_mfma_f32_32x32x16_bf16 (half the instructions, ~17% less MFMA-pipe
// time for identical LDS traffic). Wave tile 64x64 = 2x2 of 32x32.
// A/B frag: row=lane&31, k=(lane>>5)*8+j (extends the verified 16x16 pattern).
// C/D: col=lane&31, row=(reg&3)+8*(reg>>2)+4*(lane>>5) (m74/m101-verified).
// EPI: 0 = bf16 hi/lo pair (C0,C1); 1 = float*cscale (C0)
template <int EPI, int LB, bool SWAP>
__global__ __launch_bounds__(256, LB) void k_gemm32(
    const bf16* __restrict__ Ah, const bf16* __restrict__ Al,
    const bf16* __restrict__ Bh, const bf16* __restrict__ Bl,
    void* __restrict__ C0, void* __restrict__ C1,
    int Kdim, int lda, int ldb, int ldc,
    long long sA, long long sB, long long sC, float cscale) {
  __shared__ __align__(16) bf16 smm[4 * 128 * 64];
  bf16* smAh = smm;
  bf16* smBh = smm + 8192;
  bf16* smAl = smm + 16384;
  bf16* smBl = smm + 24576;

  const int tid = threadIdx.x;
  const int lane = tid & 63, wid = tid >> 6;
  const int lr32 = lane & 31, lq32 = lane >> 5;
  const int wr = (wid >> 1) * 64, wc = (wid & 1) * 64;
  const long long bz = blockIdx.z;
  const int bx = SWAP ? blockIdx.y : blockIdx.x;
  const int by = SWAP ? blockIdx.x : blockIdx.y;
  const int col0 = bx * 128, row0 = by * 128;

  const bf16* pAh = Ah + bz * sA;
  const bf16* pBh = Bh + bz * sB;
  const bf16* pAl = Al + bz * sA;
  const bf16* pBl = Bl + bz * sB;

  f32x16 acc[2][2] = {};

  for (int kt = 0; kt < Kdim; kt += 64) {
    {
      int o = tid * 16;
#pragma unroll
      for (int r = 0; r < 4; r++, o += 4096) {
        int row = o >> 7;
        int c = (o & 127) ^ ((row & 7) << 4);  // inverse swizzle on source
        gld16((const char*)(pAh + (size_t)(row0 + row) * lda + kt) + c, (char*)smAh + o);
        gld16((const char*)(pBh + (size_t)(col0 + row) * ldb + kt) + c, (char*)smBh + o);
        gld16((const char*)(pAl + (size_t)(row0 + row) * lda + kt) + c, (char*)smAl + o);
        gld16((const char*)(pBl + (size_t)(col0 + row) * ldb + kt) + c, (char*)smBl + o);
      }
    }
    __syncthreads();
#pragma unroll
    for (int s = 0; s < 4; s++) {  // 4 K-slices of 16
      bf16x8 ah[2], al[2], bh[2], bl[2];
#pragma unroll
      for (int t = 0; t < 2; t++) {
        int ar = wr + t * 32 + lr32;
        int ao = ar * 128 + ((s * 32 + lq32 * 16) ^ ((ar & 7) << 4));
        ah[t] = *(const bf16x8*)((const char*)smAh + ao);
        al[t] = *(const bf16x8*)((const char*)smAl + ao);
        int br = wc + t * 32 + lr32;
        int bo = br * 128 + ((s * 32 + lq32 * 16) ^ ((br & 7) << 4));
        bh[t] = *(const bf16x8*)((const char*)smBh + bo);
        bl[t] = *(const bf16x8*)((const char*)smBl + bo);
      }
      // product-major order: dep distance 4 between writes to the same acc
#pragma unroll
      for (int t = 0; t < 2; t++)
#pragma unroll
        for (int u = 0; u < 2; u++)
          acc[t][u] = __builtin_amdgcn_mfma_f32_32x32x16_bf16(ah[t], bh[u], acc[t][u], 0, 0, 0);
#pragma unroll
      for (int t = 0; t < 2; t++)
#pragma unroll
        for (int u = 0; u < 2; u++)
          acc[t][u] = __builtin_amdgcn_mfma_f32_32x32x16_bf16(ah[t], bl[u], acc[t][u], 0, 0, 0);
#pragma unroll
      for (int t = 0; t < 2; t++)
#pragma unroll
        for (int u = 0; u < 2; u++)
          acc[t][u] = __builtin_amdgcn_mfma_f32_32x32x16_bf16(al[t], bh[u], acc[t][u], 0, 0, 0);
    }
    __syncthreads();
  }

  // C/D: col = lane&31, row = (reg&3) + 8*(reg>>2) + 4*(lane>>5)
#pragma unroll
  for (int t = 0; t < 2; t++) {
#pragma unroll
    for (int u = 0; u < 2; u++) {
      f32x16 v = acc[t][u];
#pragma unroll
      for (int reg = 0; reg < 16; reg++) {
        int crow = (reg & 3) + 8 * (reg >> 2) + 4 * lq32;
        size_t r = (size_t)(row0 + wr + t * 32 + crow);
        size_t c = (size_t)(col0 + wc + u * 32 + lr32);
        size_t idx = r * (size_t)ldc + c;
        float val = v[reg] * cscale;
        if constexpr (EPI == 0) {
          bf16* Chp = (bf16*)C0 + bz * sC;
          bf16* Clp = (bf16*)C1 + bz * sC;
          bf16 h = (bf16)val;
          Chp[idx] = h;
          Clp[idx] = (bf16)(val - (float)h);
        } else {
          float* Cp = (float*)C0 + bz * sC;
          Cp[idx] = val;
        }
      }
    }
  }
}

// ---------------- 128^2 GEMM (round-2/8/14 structure, proven) — non-split users ----------------
// EPI: 1 = float*cscale (C0); 2 = bf16 (C0)
template <bool SPLIT, int EPI, int LB, bool SWAP>
__global__ __launch_bounds__(256, LB) void k_gemm(
    const bf16* __restrict__ Ah, const bf16* __restrict__ Al,
    const bf16* __restrict__ Bh, const bf16* __restrict__ Bl,
    void* __restrict__ C0, void* __restrict__ C1,
    int Kdim, int lda, int ldb, int ldc,
    long long sA, long long sB, long long sC, float cscale) {
  constexpr int NTILES = SPLIT ? 4 : 2;
  __shared__ __align__(16) bf16 smm[NTILES * 128 * 64];
  bf16* smAh = smm;
  bf16* smBh = smm + 8192;
  bf16* smAl = SPLIT ? smm + 16384 : nullptr;
  bf16* smBl = SPLIT ? smm + 24576 : nullptr;

  const int tid = threadIdx.x;
  const int lane = tid & 63, wid = tid >> 6;
  const int lr = lane & 15, lq = lane >> 4;
  const int wr = (wid >> 1) * 64, wc = (wid & 1) * 64;
  const long long bz = blockIdx.z;
  const int bx = SWAP ? blockIdx.y : blockIdx.x;
  const int by = SWAP ? blockIdx.x : blockIdx.y;
  const int col0 = bx * 128, row0 = by * 128;

  const bf16* pAh = Ah + bz * sA;
  const bf16* pBh = Bh + bz * sB;
  const bf16* pAl = SPLIT ? (Al + bz * sA) : nullptr;
  const bf16* pBl = SPLIT ? (Bl + bz * sB) : nullptr;

  f32x4 acc[4][4] = {};

  for (int kt = 0; kt < Kdim; kt += 64) {
    {
      int o = tid * 16;
#pragma unroll
      for (int r = 0; r < 4; r++, o += 4096) {
        int row = o >> 7;
        int c = (o & 127) ^ ((row & 7) << 4);  // inverse swizzle on source
        gld16((const char*)(pAh + (size_t)(row0 + row) * lda + kt) + c, (char*)smAh + o);
        gld16((const char*)(pBh + (size_t)(col0 + row) * ldb + kt) + c, (char*)smBh + o);
        if constexpr (SPLIT) {
          gld16((const char*)(pAl + (size_t)(row0 + row) * lda + kt) + c, (char*)smAl + o);
          gld16((const char*)(pBl + (size_t)(col0 + row) * ldb + kt) + c, (char*)smBl + o);
        }
      }
    }
    __syncthreads();
#pragma unroll
    for (int kk = 0; kk < 2; kk++) {
      bf16x8 ah[4], bh[4], al[4], bl[4];
#pragma unroll
      for (int i = 0; i < 4; i++) {
        int ar = wr + i * 16 + lr;
        int ao = ar * 128 + ((kk * 64 + lq * 16) ^ ((ar & 7) << 4));
        ah[i] = *(const bf16x8*)((const char*)smAh + ao);
        int br = wc + i * 16 + lr;
        int bo = br * 128 + ((kk * 64 + lq * 16) ^ ((br & 7) << 4));
        bh[i] = *(const bf16x8*)((const char*)smBh + bo);
        if constexpr (SPLIT) {
          al[i] = *(const bf16x8*)((const char*)smAl + ao);
          bl[i] = *(const bf16x8*)((const char*)smBl + bo);
        }
      }
#pragma unroll
      for (int i = 0; i < 4; i++)
#pragma unroll
        for (int j = 0; j < 4; j++) {
          acc[i][j] = __builtin_amdgcn_mfma_f32_16x16x32_bf16(ah[i], bh[j], acc[i][j], 0, 0, 0);
          if constexpr (SPLIT) {
            acc[i][j] = __builtin_amdgcn_mfma_f32_16x16x32_bf16(ah[i], bl[j], acc[i][j], 0, 0, 0);
            acc[i][j] = __builtin_amdgcn_mfma_f32_16x16x32_bf16(al[i], bh[j], acc[i][j], 0, 0, 0);
          }
        }
    }
    __syncthreads();
  }

  // C/D layout: row = (lane>>4)*4 + reg, col = lane&15 (verified)
#pragma unroll
  for (int i = 0; i < 4; i++) {
#pragma unroll
    for (int j2 = 0; j2 < 4; j2++) {
      f32x4 v = acc[i][j2];
#pragma unroll
      for (int j = 0; j < 4; j++) {
        size_t r = (size_t)(row0 + wr + i * 16 + lq * 4 + j);
        size_t c = (size_t)(col0 + wc + j2 * 16 + lr);
        size_t idx = r * (size_t)ldc + c;
        float val = v[j] * cscale;
        if constexpr (EPI == 1) {
          float* Cp = (float*)C0 + bz * sC;
          Cp[idx] = val;
        } else {
          bf16* Cp = (bf16*)C0 + bz * sC;
          Cp[idx] = (bf16)val;
        }
      }
    }
  }
}

// ---------------- row softmax in-place: S row fp32 -> P bf16 in first half ----------------
__global__ __launch_bounds__(256) void k_softmax(float* __restrict__ S) {
  size_t row = blockIdx.x;
  float* srow = S + row * (size_t)NN;
  int tid = threadIdx.x;
  int wid = tid >> 6, lane = tid & 63;
  const float4* s4 = (const float4*)srow;
  float4 v0 = s4[tid * 2], v1 = s4[tid * 2 + 1];
  float vv[8] = {v0.x, v0.y, v0.z, v0.w, v1.x, v1.y, v1.z, v1.w};
  float m = vv[0];
#pragma unroll
  for (int j = 1; j < 8; j++) m = fmaxf(m, vv[j]);
#pragma unroll
  for (int d = 1; d < 64; d <<= 1) m = fmaxf(m, __shfl_xor(m, d));
  __shared__ float red[8];
  if (lane == 0) red[wid] = m;
  __syncthreads();
  m = fmaxf(fmaxf(red[0], red[1]), fmaxf(red[2], red[3]));
  float e[8];
  float ssum = 0.f;
#pragma unroll
  for (int j = 0; j < 8; j++) { e[j] = __expf(vv[j] - m); ssum += e[j]; }
#pragma unroll
  for (int d = 1; d < 64; d <<= 1) ssum += __shfl_xor(ssum, d);
  if (lane == 0) red[4 + wid] = ssum;
  __syncthreads();
  ssum = red[4] + red[5] + red[6] + red[7];
  float inv = 1.0f / ssum;
  bf16x8 p;
#pragma unroll
  for (int j = 0; j < 8; j++) p[j] = (bf16)(e[j] * inv);
  // all loads of this row happened before the barriers above -> in-place safe
  *(bf16x8*)((bf16*)srow + tid * 8) = p;
}

// ---------------- host ----------------
extern "C" void kernel_launch(void* const* d_in, const int* in_sizes, int n_in,
                              void* d_out, int out_size, void* d_ws, size_t ws_size,
                              hipStream_t stream) {
  const float* x  = (const float*)d_in[0];
  const float* Wq = (const float*)d_in[1];
  const float* Wk = (const float*)d_in[2];
  const float* Wv = (const float*)d_in[3];
  const float* Wo = (const float*)d_in[4];
  float* out = (float*)d_out;
  char* ws = (char*)d_ws;

  const size_t szXE = (size_t)MM * EE * 2;      // 25.17 MB
  const size_t szWb = (size_t)EE * EE * 2;      // 1.18 MB
  const size_t szS1 = (size_t)NN * NN * 4;      // 16.78 MB

  // Layout: [xhi][xlo][Yh][Yl][Ut][ S ... ]; weight buffers OVERLAY the S slab
  bf16* xhi = (bf16*)(ws);                      // LIVE through attention (QK^T B-operand)
  bf16* xlo = (bf16*)(ws + szXE);
  bf16* Yh  = (bf16*)(ws + 2 * szXE);           // Y = x@Wqk [M][768] hi
  bf16* Yl  = (bf16*)(ws + 3 * szXE);
  bf16* Ut  = (bf16*)(ws + 4 * szXE);           // [768][16384], batches along cols
  char* Sb  = ws + 5 * szXE;
  float* S  = (float*)Sb;                       // [G][N][N] fp32; P bf16 in first half of rows
  char* wb  = Sb;                               // weight scratch overlays S
  bf16* wqTh = (bf16*)(wb);
  bf16* wqTl = (bf16*)(wb + 1 * szWb);
  bf16* wkTh = (bf16*)(wb + 2 * szWb);
  bf16* wkTl = (bf16*)(wb + 3 * szWb);
  bf16* wvT  = (bf16*)(wb + 4 * szWb);
  bf16* wob  = (bf16*)(wb + 5 * szWb);
  bf16* wqkTh = (bf16*)(wb + 6 * szWb);         // Wqk^T [j][e] hi  (Wqk = Wq^T Wk)
  bf16* wqkTl = (bf16*)(wb + 7 * szWb);
  bf16* wvob  = (bf16*)(wb + 8 * szWb);         // Wvo = Wo@Wv [g][e]

  size_t oS = (size_t)(Sb - ws);
  size_t avail = ws_size > oS ? ws_size - oS : 0;
  int G = 8;
  while (G > 1 && (size_t)G * szS1 > avail) G >>= 1;

  k_splitx<<<2048, 256, 0, stream>>>((const float4*)x, (bf16x4*)xhi, (bf16x4*)xlo, MM * EE / 4);
  k_prep<<<dim3(12, 12, 4), 256, 0, stream>>>(Wq, Wk, Wv, Wo,
                                              wqTh, wqTl, wkTh, wkTl, wvT, wob);

  // WqkT[j][e] = sum_f Wk[f][j] * Wq[f][e]  (split, 32x32 variant)
  k_gemm32<0, 2, false><<<dim3(EE / 128, EE / 128, 1), 256, 0, stream>>>(
      wkTh, wkTl, wqTh, wqTl, wqkTh, wqkTl, EE, EE, EE, EE, 0, 0, 0, 1.0f);
  // Wvo = Wo @ Wv
  k_gemm<false, 2, 4, false><<<dim3(EE / 128, EE / 128, 1), 256, 0, stream>>>(
      wob, nullptr, wvT, nullptr, wvob, nullptr, EE, EE, EE, EE, 0, 0, 0, 1.0f);
  // Y = x @ Wqk  (split 32x32, SWAP: stream x panels once, Wqk pair L2-resident)
  k_gemm32<0, 2, true><<<dim3(MM / 128, EE / 128, 1), 256, 0, stream>>>(
      xhi, xlo, wqkTh, wqkTl, Yh, Yl, EE, EE, EE, EE, 0, 0, 0, 1.0f);
  // U projection, pre-transposed: Ut[g][n] = sum_e Wvo[g][e] * x[n][e]
  k_gemm<false, 2, 4, false><<<dim3(MM / 128, EE / 128, 1), 256, 0, stream>>>(
      wvob, nullptr, xhi, nullptr, Ut, nullptr, EE, EE, EE, MM, 0, 0, 0, 1.0f);

  const long long sNE = (long long)NN * EE;
  for (int g = 0; g < BB; g += G) {
    // S = 8 * Y @ x^T  (split pair x split pair; 32x32 variant)
    k_gemm32<1, 2, false><<<dim3(NN / 128, NN / 128, G), 256, 0, stream>>>(
        Yh + (size_t)g * sNE, Yl + (size_t)g * sNE,
        xhi + (size_t)g * sNE, xlo + (size_t)g * sNE,
        S, nullptr, EE, EE, EE, NN, sNE, sNE, (long long)NN * NN, 8.0f);
    // softmax rows, P bf16 in-place
    k_softmax<<<G * NN, 256, 0, stream>>>(S);
    // out = P @ U : A = P strided in S; B = Ut columns of batch g..
    k_gemm<false, 1, 4, false><<<dim3(EE / 128, NN / 128, G), 256, 0, stream>>>(
        (const bf16*)S, nullptr, Ut + (size_t)g * NN, nullptr,
        out + (size_t)g * NN * EE, nullptr, NN, 2 * NN, MM, EE,
        2LL * NN * NN, (long long)NN, (long long)NN * EE, 1.0f);
  }
}

// Round 18
// 391.330 us; speedup vs baseline: 1.0973x; 1.0973x over previous
//
#include <hip/hip_runtime.h>
#include <stdint.h>

typedef __bf16 bf16;
typedef __bf16 bf16x4 __attribute__((ext_vector_type(4)));
typedef __bf16 bf16x8 __attribute__((ext_vector_type(8)));
typedef float  f32x4  __attribute__((ext_vector_type(4)));

constexpr int BB = 8;
constexpr int NN = 2048;
constexpr int EE = 768;
constexpr int MM = BB * NN;   // 16384

typedef const __attribute__((address_space(1))) void* as1_cvp;
typedef __attribute__((address_space(3))) void* as3_vp;

static __device__ __forceinline__ void gld16(const void* g, void* l) {
  __builtin_amdgcn_global_load_lds((as1_cvp)g, (as3_vp)l, 16, 0, 0);
}

// ---------------- x -> bf16 hi/lo split ----------------
__global__ __launch_bounds__(256) void k_splitx(const float4* __restrict__ x,
                                                bf16x4* __restrict__ hi,
                                                bf16x4* __restrict__ lo, int n4) {
  int i = blockIdx.x * 256 + threadIdx.x;
  int st = gridDim.x * 256;
  for (; i < n4; i += st) {
    float4 v = x[i];
    bf16x4 h, l;
    h[0] = (bf16)v.x; l[0] = (bf16)(v.x - (float)h[0]);
    h[1] = (bf16)v.y; l[1] = (bf16)(v.y - (float)h[1]);
    h[2] = (bf16)v.z; l[2] = (bf16)(v.z - (float)h[2]);
    h[3] = (bf16)v.w; l[3] = (bf16)(v.w - (float)h[3]);
    hi[i] = h; lo[i] = l;
  }
}

// ---------------- merged weight prep ----------------
// z: 0 = Wq^T pair, 1 = Wk^T pair, 2 = Wv^T (hi only), 3 = Wo plain cvt
__global__ __launch_bounds__(256) void k_prep(const float* __restrict__ wq,
                                              const float* __restrict__ wk,
                                              const float* __restrict__ wv,
                                              const float* __restrict__ wo,
                                              bf16* __restrict__ qTh, bf16* __restrict__ qTl,
                                              bf16* __restrict__ kTh, bf16* __restrict__ kTl,
                                              bf16* __restrict__ vT,  bf16* __restrict__ ob) {
  __shared__ float t[64][65];
  int z = blockIdx.z;
  int tid = threadIdx.x;
  if (z == 3) {  // Wo: plain fp32 -> bf16, coalesced
    int blk = blockIdx.y * 12 + blockIdx.x;
    const float4* s4 = (const float4*)wo;
#pragma unroll
    for (int j = 0; j < 4; j++) {
      int i = blk * 1024 + j * 256 + tid;
      float4 v = s4[i];
      bf16x4 h;
      h[0] = (bf16)v.x; h[1] = (bf16)v.y; h[2] = (bf16)v.z; h[3] = (bf16)v.w;
      ((bf16x4*)ob)[i] = h;
    }
    return;
  }
  const float* src = z == 0 ? wq : (z == 1 ? wk : wv);
  bf16* hi = z == 0 ? qTh : (z == 1 ? kTh : vT);
  bf16* lo = z == 0 ? qTl : kTl;  // unused when z==2
  bool pair = z < 2;
  int e0 = blockIdx.x * 64, f0 = blockIdx.y * 64;
#pragma unroll
  for (int h = 0; h < 4; h++) {
    int lin = h * 1024 + tid * 4;
    int r = lin >> 6, c = lin & 63;
    float4 v = *(const float4*)(src + (size_t)(f0 + r) * EE + e0 + c);
    t[r][c] = v.x; t[r][c + 1] = v.y; t[r][c + 2] = v.z; t[r][c + 3] = v.w;
  }
  __syncthreads();
#pragma unroll
  for (int h = 0; h < 4; h++) {
    int lin = h * 1024 + tid * 4;
    int er = lin >> 6, fc = lin & 63;
    bf16x4 oh, ol;
#pragma unroll
    for (int j = 0; j < 4; j++) {
      float v = t[fc + j][er];
      bf16 hh = (bf16)v;
      oh[j] = hh;
      ol[j] = (bf16)(v - (float)hh);
    }
    *(bf16x4*)(hi + (size_t)(e0 + er) * EE + f0 + fc) = oh;
    if (pair) *(bf16x4*)(lo + (size_t)(e0 + er) * EE + f0 + fc) = ol;
  }
}

// ---------------- 128^2 GEMM (round-2/8/14/16 structure, proven) ----------------
// C[M,N] = A[M,K] @ B[N,K]^T ; SPLIT: 3-product bf16 compensation (hi*hi+hi*lo+lo*hi)
// EPI: 0 = bf16 hi/lo pair (C0,C1); 1 = float*cscale (C0); 2 = bf16 (C0)
// SWAP: blockIdx.x indexes rows (L2: consecutive blocks stream distinct A panels,
//       B panel stays resident)
template <bool SPLIT, int EPI, int LB, bool SWAP>
__global__ __launch_bounds__(256, LB) void k_gemm(
    const bf16* __restrict__ Ah, const bf16* __restrict__ Al,
    const bf16* __restrict__ Bh, const bf16* __restrict__ Bl,
    void* __restrict__ C0, void* __restrict__ C1,
    int Kdim, int lda, int ldb, int ldc,
    long long sA, long long sB, long long sC, float cscale) {
  constexpr int NTILES = SPLIT ? 4 : 2;
  __shared__ __align__(16) bf16 smm[NTILES * 128 * 64];
  bf16* smAh = smm;
  bf16* smBh = smm + 8192;
  bf16* smAl = SPLIT ? smm + 16384 : nullptr;
  bf16* smBl = SPLIT ? smm + 24576 : nullptr;

  const int tid = threadIdx.x;
  const int lane = tid & 63, wid = tid >> 6;
  const int lr = lane & 15, lq = lane >> 4;
  const int wr = (wid >> 1) * 64, wc = (wid & 1) * 64;
  const long long bz = blockIdx.z;
  const int bx = SWAP ? blockIdx.y : blockIdx.x;
  const int by = SWAP ? blockIdx.x : blockIdx.y;
  const int col0 = bx * 128, row0 = by * 128;

  const bf16* pAh = Ah + bz * sA;
  const bf16* pBh = Bh + bz * sB;
  const bf16* pAl = SPLIT ? (Al + bz * sA) : nullptr;
  const bf16* pBl = SPLIT ? (Bl + bz * sB) : nullptr;

  f32x4 acc[4][4] = {};

  for (int kt = 0; kt < Kdim; kt += 64) {
    {
      int o = tid * 16;
#pragma unroll
      for (int r = 0; r < 4; r++, o += 4096) {
        int row = o >> 7;
        int c = (o & 127) ^ ((row & 7) << 4);  // inverse swizzle on source
        gld16((const char*)(pAh + (size_t)(row0 + row) * lda + kt) + c, (char*)smAh + o);
        gld16((const char*)(pBh + (size_t)(col0 + row) * ldb + kt) + c, (char*)smBh + o);
        if constexpr (SPLIT) {
          gld16((const char*)(pAl + (size_t)(row0 + row) * lda + kt) + c, (char*)smAl + o);
          gld16((const char*)(pBl + (size_t)(col0 + row) * ldb + kt) + c, (char*)smBl + o);
        }
      }
    }
    __syncthreads();
#pragma unroll
    for (int kk = 0; kk < 2; kk++) {
      bf16x8 ah[4], bh[4], al[4], bl[4];
#pragma unroll
      for (int i = 0; i < 4; i++) {
        int ar = wr + i * 16 + lr;
        int ao = ar * 128 + ((kk * 64 + lq * 16) ^ ((ar & 7) << 4));
        ah[i] = *(const bf16x8*)((const char*)smAh + ao);
        int br = wc + i * 16 + lr;
        int bo = br * 128 + ((kk * 64 + lq * 16) ^ ((br & 7) << 4));
        bh[i] = *(const bf16x8*)((const char*)smBh + bo);
        if constexpr (SPLIT) {
          al[i] = *(const bf16x8*)((const char*)smAl + ao);
          bl[i] = *(const bf16x8*)((const char*)smBl + bo);
        }
      }
#pragma unroll
      for (int i = 0; i < 4; i++)
#pragma unroll
        for (int j = 0; j < 4; j++) {
          acc[i][j] = __builtin_amdgcn_mfma_f32_16x16x32_bf16(ah[i], bh[j], acc[i][j], 0, 0, 0);
          if constexpr (SPLIT) {
            acc[i][j] = __builtin_amdgcn_mfma_f32_16x16x32_bf16(ah[i], bl[j], acc[i][j], 0, 0, 0);
            acc[i][j] = __builtin_amdgcn_mfma_f32_16x16x32_bf16(al[i], bh[j], acc[i][j], 0, 0, 0);
          }
        }
    }
    __syncthreads();
  }

  // C/D layout: row = (lane>>4)*4 + reg, col = lane&15 (verified)
#pragma unroll
  for (int i = 0; i < 4; i++) {
#pragma unroll
    for (int j2 = 0; j2 < 4; j2++) {
      f32x4 v = acc[i][j2];
#pragma unroll
      for (int j = 0; j < 4; j++) {
        size_t r = (size_t)(row0 + wr + i * 16 + lq * 4 + j);
        size_t c = (size_t)(col0 + wc + j2 * 16 + lr);
        size_t idx = r * (size_t)ldc + c;
        float val = v[j] * cscale;
        if constexpr (EPI == 0) {
          bf16* Chp = (bf16*)C0 + bz * sC;
          bf16* Clp = (bf16*)C1 + bz * sC;
          bf16 h = (bf16)val;
          Chp[idx] = h;
          Clp[idx] = (bf16)(val - (float)h);
        } else if constexpr (EPI == 1) {
          float* Cp = (float*)C0 + bz * sC;
          Cp[idx] = val;
        } else {
          bf16* Cp = (bf16*)C0 + bz * sC;
          Cp[idx] = (bf16)val;
        }
      }
    }
  }
}

// ---------------- row softmax in-place: S row fp32 -> P bf16 in first half ----------------
__global__ __launch_bounds__(256) void k_softmax(float* __restrict__ S) {
  size_t row = blockIdx.x;
  float* srow = S + row * (size_t)NN;
  int tid = threadIdx.x;
  int wid = tid >> 6, lane = tid & 63;
  const float4* s4 = (const float4*)srow;
  float4 v0 = s4[tid * 2], v1 = s4[tid * 2 + 1];
  float vv[8] = {v0.x, v0.y, v0.z, v0.w, v1.x, v1.y, v1.z, v1.w};
  float m = vv[0];
#pragma unroll
  for (int j = 1; j < 8; j++) m = fmaxf(m, vv[j]);
#pragma unroll
  for (int d = 1; d < 64; d <<= 1) m = fmaxf(m, __shfl_xor(m, d));
  __shared__ float red[8];
  if (lane == 0) red[wid] = m;
  __syncthreads();
  m = fmaxf(fmaxf(red[0], red[1]), fmaxf(red[2], red[3]));
  float e[8];
  float ssum = 0.f;
#pragma unroll
  for (int j = 0; j < 8; j++) { e[j] = __expf(vv[j] - m); ssum += e[j]; }
#pragma unroll
  for (int d = 1; d < 64; d <<= 1) ssum += __shfl_xor(ssum, d);
  if (lane == 0) red[4 + wid] = ssum;
  __syncthreads();
  ssum = red[4] + red[5] + red[6] + red[7];
  float inv = 1.0f / ssum;
  bf16x8 p;
#pragma unroll
  for (int j = 0; j < 8; j++) p[j] = (bf16)(e[j] * inv);
  // all loads of this row happened before the barriers above -> in-place safe
  *(bf16x8*)((bf16*)srow + tid * 8) = p;
}

// ---------------- host ----------------
extern "C" void kernel_launch(void* const* d_in, const int* in_sizes, int n_in,
                              void* d_out, int out_size, void* d_ws, size_t ws_size,
                              hipStream_t stream) {
  const float* x  = (const float*)d_in[0];
  const float* Wq = (const float*)d_in[1];
  const float* Wk = (const float*)d_in[2];
  const float* Wv = (const float*)d_in[3];
  const float* Wo = (const float*)d_in[4];
  float* out = (float*)d_out;
  char* ws = (char*)d_ws;

  const size_t szXE = (size_t)MM * EE * 2;      // 25.17 MB
  const size_t szWb = (size_t)EE * EE * 2;      // 1.18 MB
  const size_t szS1 = (size_t)NN * NN * 4;      // 16.78 MB

  // Layout: [xhi][xlo][Yh][Yl][Ut][ S ... ]; weight buffers OVERLAY the S slab
  // (weights dead before the first S write) -> oS = 5*szXE ~ 126 MB -> G=8 fits.
  bf16* xhi = (bf16*)(ws);                      // LIVE through attention (QK^T B-operand)
  bf16* xlo = (bf16*)(ws + szXE);
  bf16* Yh  = (bf16*)(ws + 2 * szXE);           // Y = x@Wqk [M][768] hi
  bf16* Yl  = (bf16*)(ws + 3 * szXE);
  bf16* Ut  = (bf16*)(ws + 4 * szXE);           // [768][16384], batches along cols
  char* Sb  = ws + 5 * szXE;
  float* S  = (float*)Sb;                       // [G][N][N] fp32; P bf16 in first half of rows
  char* wb  = Sb;                               // weight scratch overlays S
  bf16* wqTh = (bf16*)(wb);
  bf16* wqTl = (bf16*)(wb + 1 * szWb);
  bf16* wkTh = (bf16*)(wb + 2 * szWb);
  bf16* wkTl = (bf16*)(wb + 3 * szWb);
  bf16* wvT  = (bf16*)(wb + 4 * szWb);
  bf16* wob  = (bf16*)(wb + 5 * szWb);
  bf16* wqkTh = (bf16*)(wb + 6 * szWb);         // Wqk^T [j][e] hi  (Wqk = Wq^T Wk)
  bf16* wqkTl = (bf16*)(wb + 7 * szWb);
  bf16* wvob  = (bf16*)(wb + 8 * szWb);         // Wvo = Wo@Wv [g][e]

  size_t oS = (size_t)(Sb - ws);
  size_t avail = ws_size > oS ? ws_size - oS : 0;
  int G = 8;
  while (G > 1 && (size_t)G * szS1 > avail) G >>= 1;

  k_splitx<<<2048, 256, 0, stream>>>((const float4*)x, (bf16x4*)xhi, (bf16x4*)xlo, MM * EE / 4);
  k_prep<<<dim3(12, 12, 4), 256, 0, stream>>>(Wq, Wk, Wv, Wo,
                                              wqTh, wqTl, wkTh, wkTl, wvT, wob);

  // WqkT[j][e] = sum_f Wk[f][j] * Wq[f][e]  (proven config)
  k_gemm<true, 0, 2, false><<<dim3(EE / 128, EE / 128, 1), 256, 0, stream>>>(
      wkTh, wkTl, wqTh, wqTl, wqkTh, wqkTl, EE, EE, EE, EE, 0, 0, 0, 1.0f);
  // Wvo = Wo @ Wv
  k_gemm<false, 2, 4, false><<<dim3(EE / 128, EE / 128, 1), 256, 0, stream>>>(
      wob, nullptr, wvT, nullptr, wvob, nullptr, EE, EE, EE, EE, 0, 0, 0, 1.0f);
  // Y = x @ Wqk  (SWAP: stream x panels once, Wqk pair L2-resident — round-14 win)
  k_gemm<true, 0, 2, true><<<dim3(MM / 128, EE / 128, 1), 256, 0, stream>>>(
      xhi, xlo, wqkTh, wqkTl, Yh, Yl, EE, EE, EE, EE, 0, 0, 0, 1.0f);
  // U projection, pre-transposed: Ut[g][n] = sum_e Wvo[g][e] * x[n][e]
  k_gemm<false, 2, 4, false><<<dim3(MM / 128, EE / 128, 1), 256, 0, stream>>>(
      wvob, nullptr, xhi, nullptr, Ut, nullptr, EE, EE, EE, MM, 0, 0, 0, 1.0f);

  const long long sNE = (long long)NN * EE;
  for (int g = 0; g < BB; g += G) {
    // S = 8 * Y @ x^T  (split pair x split pair; proven config)
    k_gemm<true, 1, 2, false><<<dim3(NN / 128, NN / 128, G), 256, 0, stream>>>(
        Yh + (size_t)g * sNE, Yl + (size_t)g * sNE,
        xhi + (size_t)g * sNE, xlo + (size_t)g * sNE,
        S, nullptr, EE, EE, EE, NN, sNE, sNE, (long long)NN * NN, 8.0f);
    // softmax rows, P bf16 in-place
    k_softmax<<<G * NN, 256, 0, stream>>>(S);
    // out = P @ U : A = P strided in S; B = Ut columns of batch g..
    k_gemm<false, 1, 4, false><<<dim3(EE / 128, NN / 128, G), 256, 0, stream>>>(
        (const bf16*)S, nullptr, Ut + (size_t)g * NN, nullptr,
        out + (size_t)g * NN * EE, nullptr, NN, 2 * NN, MM, EE,
        2LL * NN * NN, (long long)NN, (long long)NN * EE, 1.0f);
  }
}